// Round 10
// baseline (1616.623 us; speedup 1.0000x reference)
//
#include <hip/hip_runtime.h>

#define NN    60000
#define NODES 100000
#define DD    64
#define NNZ   3200000
#define BB    1024
#define NEG   0.2f
#define RPB   196                        // rows per bucket
#define NBUCK 511                        // ceil(NODES/RPB)
#define EPB   8192                       // edges per sort block
#define NPB   ((NNZ + EPB - 1) / EPB)    // 391
#define CAP   7000                       // bucket capacity (mean 6272, sd~79)
#define BCAP  7168                       // LDS edge capacity in k_csr
#define NSEG  13                         // column segments (col>>13), ~2 MB x-slice each
#define KEYN  (NSEG * RPB)               // 2548 sort keys per bucket
#define SPB   (KEYN + 1)                 // starts entries per bucket

// ---------------------------------------------------------------- init xa = concat(eu, ei); also init gcur
__global__ __launch_bounds__(256) void k_init_x(const float* __restrict__ eu,
                                                const float* __restrict__ ei,
                                                float* __restrict__ x,
                                                int* __restrict__ gcur) {
    int i = blockIdx.x * 256 + threadIdx.x;          // float4 index
    if (i < NBUCK) gcur[i] = i * CAP;
    const int TOT = NODES * DD / 4;
    if (i >= TOT) return;
    const int UE = NN * DD / 4;
    float4 v = (i < UE) ? ((const float4*)eu)[i] : ((const float4*)ei)[i - UE];
    ((float4*)x)[i] = v;
}

// ---------------------------------------------------------------- bucket sort -> bulk
__global__ __launch_bounds__(512) void k_place(const int* __restrict__ row,
                                               const int* __restrict__ col,
                                               const float* __restrict__ val,
                                               int* __restrict__ gcur,
                                               int2* __restrict__ bulk) {
    __shared__ int rows_l[EPB];                // 32 KB
    __shared__ unsigned short perm[EPB];       // 16 KB
    __shared__ int h[NBUCK], bloc[NBUCK], bcur[NBUCK], gseg[NBUCK];
    __shared__ int sc[512];
    int t = threadIdx.x;
    if (t < NBUCK) h[t] = 0;
    __syncthreads();
    int base = blockIdx.x * EPB;
    int n = min(EPB, NNZ - base);
    for (int k = t; k < n; k += 512) {
        int r = row[base + k];
        rows_l[k] = r;
        atomicAdd(&h[r / RPB], 1);
    }
    __syncthreads();
    {
        int v = (t < NBUCK) ? h[t] : 0;
        sc[t] = v;
        __syncthreads();
        for (int off = 1; off < 512; off <<= 1) {
            int u = (t >= off) ? sc[t - off] : 0;
            __syncthreads();
            sc[t] += u;
            __syncthreads();
        }
        if (t < NBUCK) {
            int ex = sc[t] - v;
            bloc[t] = ex;
            bcur[t] = ex;
            gseg[t] = v ? atomicAdd(&gcur[t], v) : 0;
        }
    }
    __syncthreads();
    for (int k = t; k < n; k += 512) {
        int p = atomicAdd(&bcur[rows_l[k] / RPB], 1);
        perm[p] = (unsigned short)k;
    }
    __syncthreads();
    for (int j = t; j < n; j += 512) {
        int k = perm[j];
        int r = rows_l[k];
        int b = r / RPB;
        int addr = gseg[b] + (j - bloc[b]);
        bulk[addr] = make_int2(((r - b * RPB) << 17) | col[base + k],
                               __float_as_int(val[base + k]));
    }
}

// ---------------------------------------------------------------- per-bucket (colseg,row) sort
// in-place (keeps packed local-row bits); emit per-key span starts + sentinel
__global__ __launch_bounds__(512) void k_csr(const int* __restrict__ gcur,
                                             int2* __restrict__ bulk,
                                             int* __restrict__ starts) {
    __shared__ int2 eds[BCAP];                 // 56 KB
    __shared__ int cnt[KEYN], pos[KEYN];       // 20 KB
    __shared__ int part[512];
    int b = blockIdx.x, t = threadIdx.x;
    int lo = b * CAP;
    int n = gcur[b] - lo;
    for (int k = t; k < KEYN; k += 512) cnt[k] = 0;
    __syncthreads();
    for (int i = t; i < n; i += 512) {
        int2 ed = bulk[lo + i];
        eds[i] = ed;
        int lr = ed.x >> 17, c = ed.x & 0x1FFFF;
        atomicAdd(&cnt[(c >> 13) * RPB + lr], 1);
    }
    __syncthreads();
    // two-level exclusive scan over KEYN bins (5 bins/thread)
    int run = 0;
#pragma unroll
    for (int j = 0; j < 5; ++j) {
        int k = t * 5 + j;
        if (k < KEYN) { pos[k] = run; run += cnt[k]; }
    }
    part[t] = run;
    __syncthreads();
    for (int off = 1; off < 512; off <<= 1) {
        int u = (t >= off) ? part[t - off] : 0;
        __syncthreads();
        part[t] += u;
        __syncthreads();
    }
    int poff = part[t] - run;
#pragma unroll
    for (int j = 0; j < 5; ++j) {
        int k = t * 5 + j;
        if (k < KEYN) pos[k] += poff;
    }
    __syncthreads();
    for (int k = t; k < KEYN; k += 512) {
        starts[b * SPB + k] = lo + pos[k];
        cnt[k] = pos[k];                      // reuse as cursor
    }
    if (t == 0) starts[b * SPB + KEYN] = lo + n;
    __syncthreads();
    for (int i = t; i < n; i += 512) {
        int2 ed = eds[i];
        int lr = ed.x >> 17, c = ed.x & 0x1FFFF;
        int p = atomicAdd(&cnt[(c >> 13) * RPB + lr], 1);
        bulk[lo + p] = ed;                    // keep packed (lr<<17 | col)
    }
}

// ---------------------------------------------------------------- fused SpMM + layer GEMM
// SpMM = the R9-measured best (~83 us): readfirstlane(wid) -> scalar loop
// control, 8 cv s_loads (SMEM/lgkmcnt) + 8 gathers (vmcnt) split-counter
// 2-deep pipeline; run-length cur/f accumulate into LDS acc.
// Epilogue: xd[r,:] = lrelu(acc[r,:]@W1 + (xs[r,:].*acc[r,:])@W2 + b1+b2)
// computed straight from LDS acc -- `lie` never touches global memory, and
// the standalone k_gemm (3 launches, 51 MB/layer round-trip) is deleted.
// Epilogue keeps VGPR low (weights reloaded per row-pass, L1-hit broadcast)
// so the 2-blocks/CU occupancy the spmm needs is preserved (LDS 50176 B).
// Race-free: reads xs, writes xd (ping-pong buffers), kernel boundary = barrier.
__global__ __launch_bounds__(1024) void k_fused(const int* __restrict__ starts,
                                                const int2* __restrict__ cv,
                                                const float* __restrict__ xs,
                                                float* __restrict__ xd,
                                                const float* __restrict__ W1,
                                                const float* __restrict__ W2,
                                                const float* __restrict__ b1,
                                                const float* __restrict__ b2) {
    __shared__ float acc[RPB * DD];            // 49 KB
    int t = threadIdx.x, b = blockIdx.x;
    float4* av = (float4*)acc;
    for (int i = t; i < RPB * 16; i += 1024) av[i] = make_float4(0.f, 0.f, 0.f, 0.f);
    __syncthreads();
    int lane = t & 63;
    int wid = __builtin_amdgcn_readfirstlane(t >> 6);   // provably wave-uniform
    int r0 = (wid * RPB) >> 4;
    int r1 = ((wid + 1) * RPB) >> 4;
    int sb = b * SPB;
    for (int seg = 0; seg < NSEG; ++seg) {
        int s = starts[sb + seg * RPB + r0];
        int e = starts[sb + seg * RPB + r1];   // r1==RPB -> next seg's r0 / sentinel
        int cur = -1;
        float f = 0.f;
        int2 emA[8], emB[8];
        float xwA[8], xwB[8];
#define LDM(S, gg) { _Pragma("unroll") \
    for (int j = 0; j < 8; ++j) em##S[j] = cv[(gg) + j]; }
#define GTH(S) { _Pragma("unroll") \
    for (int j = 0; j < 8; ++j) xw##S[j] = xs[(em##S[j].x & 0x1FFFF) * DD + lane]; }
#define CNS(S) { _Pragma("unroll") \
    for (int j = 0; j < 8; ++j) { \
        int r = em##S[j].x >> 17; \
        if (r != cur) { if (cur >= 0) acc[cur * DD + lane] += f; cur = r; f = 0.f; } \
        f = fmaf(__int_as_float(em##S[j].y), xw##S[j], f); } }
        int nb = (e - s) >> 3;                 // full 8-blocks (uniform)
        if (nb > 0) {
            LDM(A, s) GTH(A)
            int ld = 1;
            for (;;) {
                if (ld < nb) { LDM(B, s + ld * 8) GTH(B) ++ld; CNS(A) }
                else         { CNS(A) break; }
                if (ld < nb) { LDM(A, s + ld * 8) GTH(A) ++ld; CNS(B) }
                else         { CNS(B) break; }
            }
        }
#undef LDM
#undef GTH
#undef CNS
        for (int g = s + nb * 8; g < e; ++g) {
            int2 ed = cv[g];
            float xg = xs[(ed.x & 0x1FFFF) * DD + lane];
            int r = ed.x >> 17;
            if (r != cur) {
                if (cur >= 0) acc[cur * DD + lane] += f;
                cur = r; f = 0.f;
            }
            f = fmaf(__int_as_float(ed.y), xg, f);
        }
        if (cur >= 0) acc[cur * DD + lane] += f;
    }
    __syncthreads();

    // ---------------- fused GEMM epilogue ----------------
    {
        const int row0 = b * RPB;
        const int tx = t & 15;                 // col group (4 cols)
        const int ty = t >> 4;                 // 0..63
        const float4* w1v = (const float4*)W1;
        const float4* w2v = (const float4*)W2;
        float4 b1v = ((const float4*)b1)[tx];
        float4 b2v = ((const float4*)b2)[tx];
        float4 bb = make_float4(b1v.x + b2v.x, b1v.y + b2v.y,
                                b1v.z + b2v.z, b1v.w + b2v.w);
        int nr = (ty < RPB - 192) ? 4 : 3;     // 196 = 3*64 + 4; wave-uniform
        for (int i = 0; i < nr; ++i) {
            int lr = ty + i * 64;
            int gr = row0 + lr;
            bool live = (gr < NODES);
            float4 o = bb;
            const float4* lrow = (const float4*)&acc[lr * DD];
            const float4* xrow = (const float4*)&xs[(live ? gr : 0) * DD];
#pragma unroll
            for (int k4 = 0; k4 < 16; ++k4) {
                float4 l4 = lrow[k4];
                float4 x4 = xrow[k4];
#pragma unroll
                for (int kk = 0; kk < 4; ++kk) {
                    float lk = (&l4.x)[kk];
                    float ak = lk * (&x4.x)[kk];
                    float4 w1r = w1v[(k4 * 4 + kk) * 16 + tx];
                    float4 w2r = w2v[(k4 * 4 + kk) * 16 + tx];
                    o.x = fmaf(lk, w1r.x, fmaf(ak, w2r.x, o.x));
                    o.y = fmaf(lk, w1r.y, fmaf(ak, w2r.y, o.y));
                    o.z = fmaf(lk, w1r.z, fmaf(ak, w2r.z, o.z));
                    o.w = fmaf(lk, w1r.w, fmaf(ak, w2r.w, o.w));
                }
            }
            if (live) {
                o.x = o.x >= 0.f ? o.x : NEG * o.x;
                o.y = o.y >= 0.f ? o.y : NEG * o.y;
                o.z = o.z >= 0.f ? o.z : NEG * o.z;
                o.w = o.w >= 0.f ? o.w : NEG * o.w;
                ((float4*)xd)[gr * 16 + tx] = o;
            }
        }
    }
}

// ---------------------------------------------------------------- gather layer repr into output
__global__ __launch_bounds__(256) void k_gather(const float* __restrict__ x,
                                                const int* __restrict__ su,
                                                const int* __restrict__ oi,
                                                const int* __restrict__ ui,
                                                float* __restrict__ out, int layer) {
    int w    = (blockIdx.x * 256 + threadIdx.x) >> 6;
    int lane = threadIdx.x & 63;
    if (w >= 3 * BB) return;
    int g = w >> 10, b = w & 1023;
    int node = (g == 0) ? su[b] : (NN + ((g == 1) ? oi[b] : ui[b]));
    out[w * 256 + layer * 64 + lane] = x[node * DD + lane];
}

// ---------------------------------------------------------------- launch
extern "C" void kernel_launch(void* const* d_in, const int* in_sizes, int n_in,
                              void* d_out, int out_size, void* d_ws, size_t ws_size,
                              hipStream_t stream) {
    const int*   edge_row = (const int*)d_in[0];
    const int*   edge_col = (const int*)d_in[1];
    const float* edge_val = (const float*)d_in[2];
    const float* eu = (const float*)d_in[3];
    const float* ei = (const float*)d_in[4];
    const float* W1 = (const float*)d_in[5];
    const float* W2 = (const float*)d_in[6];
    const float* b1 = (const float*)d_in[7];
    const float* b2 = (const float*)d_in[8];
    const int*   su = (const int*)d_in[9];
    const int*   oi = (const int*)d_in[10];
    const int*   ui = (const int*)d_in[11];
    float* out = (float*)d_out;

    // workspace carve (~85 MB): xa/xb ping-pong (former x/lie), then sort bufs
    float* xa     = (float*)d_ws;                    // 25.6 MB
    float* xb     = xa + NODES * DD;                 // 25.6 MB (former lie)
    int2*  bulk   = (int2*)(xb + NODES * DD);        // NBUCK*CAP int2 (28.6 MB)
    int*   gcur   = (int*)(bulk + NBUCK * CAP);      // NBUCK
    int*   starts = gcur + NBUCK + 1;                // NBUCK*SPB (5.2 MB)

    k_init_x<<<(NODES * DD / 4 + 255) / 256, 256, 0, stream>>>(eu, ei, xa, gcur);
    k_gather<<<(3 * BB * 64 + 255) / 256, 256, 0, stream>>>(xa, su, oi, ui, out, 0);

    k_place<<<NPB, 512, 0, stream>>>(edge_row, edge_col, edge_val, gcur, bulk);
    k_csr<<<NBUCK, 512, 0, stream>>>(gcur, bulk, starts);

    const float* xsrc = xa;
    float*       xdst = xb;
    for (int l = 0; l < 3; ++l) {
        k_fused<<<NBUCK, 1024, 0, stream>>>(starts, bulk, xsrc, xdst,
                                            W1 + l * 4096, W2 + l * 4096,
                                            b1 + l * 64,  b2 + l * 64);
        k_gather<<<(3 * BB * 64 + 255) / 256, 256, 0, stream>>>(xdst, su, oi, ui,
                                                                out, l + 1);
        const float* tmp = xsrc; xsrc = xdst; xdst = (float*)tmp;
    }
}

// Round 11
// 632.226 us; speedup vs baseline: 2.5570x; 2.5570x over previous
//
#include <hip/hip_runtime.h>

#define NN    60000
#define NODES 100000
#define DD    64
#define NNZ   3200000
#define BB    1024
#define NEG   0.2f
#define RPB   196                        // rows per bucket
#define NBUCK 511                        // ceil(NODES/RPB)
#define EPB   8192                       // edges per sort block
#define NPB   ((NNZ + EPB - 1) / EPB)    // 391
#define CAP   7000                       // bucket capacity (mean 6272, sd~79)
#define BCAP  7168                       // LDS edge capacity in k_csr
#define NSEG  13                         // column segments (col>>13), ~2 MB x-slice each
#define KEYN  (NSEG * RPB)               // 2548 sort keys per bucket
#define SPB   (KEYN + 1)                 // starts entries per bucket

// ---------------------------------------------------------------- init xa = concat(eu, ei); also init gcur
__global__ __launch_bounds__(256) void k_init_x(const float* __restrict__ eu,
                                                const float* __restrict__ ei,
                                                float* __restrict__ x,
                                                int* __restrict__ gcur) {
    int i = blockIdx.x * 256 + threadIdx.x;          // float4 index
    if (i < NBUCK) gcur[i] = i * CAP;
    const int TOT = NODES * DD / 4;
    if (i >= TOT) return;
    const int UE = NN * DD / 4;
    float4 v = (i < UE) ? ((const float4*)eu)[i] : ((const float4*)ei)[i - UE];
    ((float4*)x)[i] = v;
}

// ---------------------------------------------------------------- bucket sort -> bulk
__global__ __launch_bounds__(512) void k_place(const int* __restrict__ row,
                                               const int* __restrict__ col,
                                               const float* __restrict__ val,
                                               int* __restrict__ gcur,
                                               int2* __restrict__ bulk) {
    __shared__ int rows_l[EPB];                // 32 KB
    __shared__ unsigned short perm[EPB];       // 16 KB
    __shared__ int h[NBUCK], bloc[NBUCK], bcur[NBUCK], gseg[NBUCK];
    __shared__ int sc[512];
    int t = threadIdx.x;
    if (t < NBUCK) h[t] = 0;
    __syncthreads();
    int base = blockIdx.x * EPB;
    int n = min(EPB, NNZ - base);
    for (int k = t; k < n; k += 512) {
        int r = row[base + k];
        rows_l[k] = r;
        atomicAdd(&h[r / RPB], 1);
    }
    __syncthreads();
    {
        int v = (t < NBUCK) ? h[t] : 0;
        sc[t] = v;
        __syncthreads();
        for (int off = 1; off < 512; off <<= 1) {
            int u = (t >= off) ? sc[t - off] : 0;
            __syncthreads();
            sc[t] += u;
            __syncthreads();
        }
        if (t < NBUCK) {
            int ex = sc[t] - v;
            bloc[t] = ex;
            bcur[t] = ex;
            gseg[t] = v ? atomicAdd(&gcur[t], v) : 0;
        }
    }
    __syncthreads();
    for (int k = t; k < n; k += 512) {
        int p = atomicAdd(&bcur[rows_l[k] / RPB], 1);
        perm[p] = (unsigned short)k;
    }
    __syncthreads();
    for (int j = t; j < n; j += 512) {
        int k = perm[j];
        int r = rows_l[k];
        int b = r / RPB;
        int addr = gseg[b] + (j - bloc[b]);
        bulk[addr] = make_int2(((r - b * RPB) << 17) | col[base + k],
                               __float_as_int(val[base + k]));
    }
}

// ---------------------------------------------------------------- per-bucket (colseg,row) sort
// in-place (keeps packed local-row bits); emit per-key span starts + sentinel
__global__ __launch_bounds__(512) void k_csr(const int* __restrict__ gcur,
                                             int2* __restrict__ bulk,
                                             int* __restrict__ starts) {
    __shared__ int2 eds[BCAP];                 // 56 KB
    __shared__ int cnt[KEYN], pos[KEYN];       // 20 KB
    __shared__ int part[512];
    int b = blockIdx.x, t = threadIdx.x;
    int lo = b * CAP;
    int n = gcur[b] - lo;
    for (int k = t; k < KEYN; k += 512) cnt[k] = 0;
    __syncthreads();
    for (int i = t; i < n; i += 512) {
        int2 ed = bulk[lo + i];
        eds[i] = ed;
        int lr = ed.x >> 17, c = ed.x & 0x1FFFF;
        atomicAdd(&cnt[(c >> 13) * RPB + lr], 1);
    }
    __syncthreads();
    // two-level exclusive scan over KEYN bins (5 bins/thread)
    int run = 0;
#pragma unroll
    for (int j = 0; j < 5; ++j) {
        int k = t * 5 + j;
        if (k < KEYN) { pos[k] = run; run += cnt[k]; }
    }
    part[t] = run;
    __syncthreads();
    for (int off = 1; off < 512; off <<= 1) {
        int u = (t >= off) ? part[t - off] : 0;
        __syncthreads();
        part[t] += u;
        __syncthreads();
    }
    int poff = part[t] - run;
#pragma unroll
    for (int j = 0; j < 5; ++j) {
        int k = t * 5 + j;
        if (k < KEYN) pos[k] += poff;
    }
    __syncthreads();
    for (int k = t; k < KEYN; k += 512) {
        starts[b * SPB + k] = lo + pos[k];
        cnt[k] = pos[k];                      // reuse as cursor
    }
    if (t == 0) starts[b * SPB + KEYN] = lo + n;
    __syncthreads();
    for (int i = t; i < n; i += 512) {
        int2 ed = eds[i];
        int lr = ed.x >> 17, c = ed.x & 0x1FFFF;
        int p = atomicAdd(&cnt[(c >> 13) * RPB + lr], 1);
        bulk[lo + p] = ed;                    // keep packed (lr<<17 | col)
    }
}

// ---------------------------------------------------------------- SpMM core macros (R9 PIPE1, measured ~83 us)
#define SPMM_BODY(XSRC, ACCDST)                                                  \
    for (int seg = 0; seg < NSEG; ++seg) {                                       \
        int s = starts[sb + seg * RPB + r0];                                     \
        int e = starts[sb + seg * RPB + r1];                                     \
        int cur = -1;                                                            \
        float f = 0.f;                                                           \
        int2 emA[8], emB[8];                                                     \
        float xwA[8], xwB[8];                                                    \
        int nb = (e - s) >> 3;                                                   \
        if (nb > 0) {                                                            \
            LDM(A, s) GTH(A, XSRC)                                               \
            int ld = 1;                                                          \
            for (;;) {                                                           \
                if (ld < nb) { LDM(B, s + ld * 8) GTH(B, XSRC) ++ld; CNS(A, ACCDST) } \
                else         { CNS(A, ACCDST) break; }                           \
                if (ld < nb) { LDM(A, s + ld * 8) GTH(A, XSRC) ++ld; CNS(B, ACCDST) } \
                else         { CNS(B, ACCDST) break; }                           \
            }                                                                    \
        }                                                                        \
        for (int g = s + nb * 8; g < e; ++g) {                                   \
            int2 ed = cv[g];                                                     \
            float xg = XSRC[(ed.x & 0x1FFFF) * DD + lane];                       \
            int r = ed.x >> 17;                                                  \
            if (r != cur) {                                                      \
                if (cur >= 0) ACCDST[cur * DD + lane] += f;                      \
                cur = r; f = 0.f;                                                \
            }                                                                    \
            f = fmaf(__int_as_float(ed.y), xg, f);                               \
        }                                                                        \
        if (cur >= 0) ACCDST[cur * DD + lane] += f;                              \
    }
#define LDM(S, gg) { _Pragma("unroll") \
    for (int j = 0; j < 8; ++j) em##S[j] = cv[(gg) + j]; }
#define GTH(S, XSRC) { _Pragma("unroll") \
    for (int j = 0; j < 8; ++j) xw##S[j] = XSRC[(em##S[j].x & 0x1FFFF) * DD + lane]; }
#define CNS(S, ACCDST) { _Pragma("unroll") \
    for (int j = 0; j < 8; ++j) { \
        int r = em##S[j].x >> 17; \
        if (r != cur) { if (cur >= 0) ACCDST[cur * DD + lane] += f; cur = r; f = 0.f; } \
        f = fmaf(__int_as_float(em##S[j].y), xw##S[j], f); } }

// ---------------------------------------------------------------- fused SpMM + layer GEMM (spill-fixed)
// R10 failure: fully-unrolled epilogue (64 iters x 2 float4 weight loads)
// blew past the 64-VGPR cap -> AGPR/scratch spills (FETCH +330 MB, WRITE
// +196 MB, Occ 40%, VALU 8%, 490 us). Fix: #pragma unroll 2 on the k4 loop
// caps live weight-loads at ~16 dwords; epilogue fits alongside the SpMM
// register set, no spill. Everything else identical to R10.
__global__ __launch_bounds__(1024) void k_fused(const int* __restrict__ starts,
                                                const int2* __restrict__ cv,
                                                const float* __restrict__ xs,
                                                float* __restrict__ xd,
                                                const float* __restrict__ W1,
                                                const float* __restrict__ W2,
                                                const float* __restrict__ b1,
                                                const float* __restrict__ b2) {
    __shared__ float acc[RPB * DD];            // 49 KB
    int t = threadIdx.x, b = blockIdx.x;
    float4* av = (float4*)acc;
    for (int i = t; i < RPB * 16; i += 1024) av[i] = make_float4(0.f, 0.f, 0.f, 0.f);
    __syncthreads();
    int lane = t & 63;
    int wid = __builtin_amdgcn_readfirstlane(t >> 6);   // provably wave-uniform
    int r0 = (wid * RPB) >> 4;
    int r1 = ((wid + 1) * RPB) >> 4;
    int sb = b * SPB;
    SPMM_BODY(xs, acc)
    __syncthreads();

    // ---------------- fused GEMM epilogue (register-bounded) ----------------
    {
        const int row0 = b * RPB;
        const int tx = t & 15;                 // col group (4 cols)
        const int ty = t >> 4;                 // 0..63
        const float4* w1v = (const float4*)W1;
        const float4* w2v = (const float4*)W2;
        float4 b1v = ((const float4*)b1)[tx];
        float4 b2v = ((const float4*)b2)[tx];
        float4 bb = make_float4(b1v.x + b2v.x, b1v.y + b2v.y,
                                b1v.z + b2v.z, b1v.w + b2v.w);
        int nr = (ty < RPB - 192) ? 4 : 3;     // 196 = 3*64 + 4; wave-uniform
        for (int i = 0; i < nr; ++i) {
            int lr = ty + i * 64;
            int gr = row0 + lr;
            bool live = (gr < NODES);
            float4 o = bb;
            const float4* lrow = (const float4*)&acc[lr * DD];
            const float4* xrow = (const float4*)&xs[(live ? gr : 0) * DD];
#pragma unroll 2
            for (int k4 = 0; k4 < 16; ++k4) {
                float4 l4 = lrow[k4];
                float4 x4 = xrow[k4];
#pragma unroll
                for (int kk = 0; kk < 4; ++kk) {
                    float lk = (&l4.x)[kk];
                    float ak = lk * (&x4.x)[kk];
                    float4 w1r = w1v[(k4 * 4 + kk) * 16 + tx];
                    float4 w2r = w2v[(k4 * 4 + kk) * 16 + tx];
                    o.x = fmaf(lk, w1r.x, fmaf(ak, w2r.x, o.x));
                    o.y = fmaf(lk, w1r.y, fmaf(ak, w2r.y, o.y));
                    o.z = fmaf(lk, w1r.z, fmaf(ak, w2r.z, o.z));
                    o.w = fmaf(lk, w1r.w, fmaf(ak, w2r.w, o.w));
                }
            }
            if (live) {
                o.x = o.x >= 0.f ? o.x : NEG * o.x;
                o.y = o.y >= 0.f ? o.y : NEG * o.y;
                o.z = o.z >= 0.f ? o.z : NEG * o.z;
                o.w = o.w >= 0.f ? o.w : NEG * o.w;
                ((float4*)xd)[gr * 16 + tx] = o;
            }
        }
    }
}

// ---------------------------------------------------------------- unfused SpMM (R9 PIPE1) -- control arm
__global__ __launch_bounds__(1024) void k_cspmm(const int* __restrict__ starts,
                                                const int2* __restrict__ cv,
                                                const float* __restrict__ xs,
                                                float* __restrict__ lie) {
    __shared__ float acc[RPB * DD];            // 49 KB
    int t = threadIdx.x, b = blockIdx.x;
    float4* av = (float4*)acc;
    for (int i = t; i < RPB * 16; i += 1024) av[i] = make_float4(0.f, 0.f, 0.f, 0.f);
    __syncthreads();
    int lane = t & 63;
    int wid = __builtin_amdgcn_readfirstlane(t >> 6);
    int r0 = (wid * RPB) >> 4;
    int r1 = ((wid + 1) * RPB) >> 4;
    int sb = b * SPB;
    SPMM_BODY(xs, acc)
    __syncthreads();
    int row0 = b * RPB;
    for (int i = t; i < RPB * 16; i += 1024) {
        int gr = row0 + (i >> 4);
        if (gr < NODES) ((float4*)lie)[gr * 16 + (i & 15)] = av[i];
    }
}
#undef LDM
#undef GTH
#undef CNS
#undef SPMM_BODY

// ---------------------------------------------------------------- layer GEMM, ping-pong variant
// reads x_in (xs) and liex (xd, holding lie), writes new x into liex in place.
// Same-pointer read->write per block-owned rows; barrier-ordered, race-free.
__global__ __launch_bounds__(256) void k_gemm_pp(const float* __restrict__ x_in,
                                                 float* __restrict__ liex,
                                                 const float* __restrict__ W1,
                                                 const float* __restrict__ W2,
                                                 const float* __restrict__ b1,
                                                 const float* __restrict__ b2) {
    __shared__ float A1[64 * 64];
    __shared__ float A2[64 * 64];
    __shared__ float Ws1[64 * 64];
    __shared__ float Ws2[64 * 64];

    const int t = threadIdx.x;
    const int row0 = blockIdx.x * 64;

    {
        const float4* w1v = (const float4*)W1;
        const float4* w2v = (const float4*)W2;
        float4* s1v = (float4*)Ws1;
        float4* s2v = (float4*)Ws2;
#pragma unroll
        for (int q = 0; q < 4; ++q) {
            s1v[q * 256 + t] = w1v[q * 256 + t];
            s2v[q * 256 + t] = w2v[q * 256 + t];
        }
    }
#pragma unroll
    for (int q = 0; q < 4; ++q) {
        int f4 = q * 256 + t;
        int rl = f4 >> 4;
        int c4 = f4 & 15;
        int gr = row0 + rl;
        float4 lv = make_float4(0.f, 0.f, 0.f, 0.f);
        float4 xv = make_float4(0.f, 0.f, 0.f, 0.f);
        if (gr < NODES) {
            lv = *(const float4*)&liex[gr * DD + c4 * 4];
            xv = *(const float4*)&x_in[gr * DD + c4 * 4];
        }
        int sg = c4 ^ (rl & 15);
        ((float4*)A1)[rl * 16 + sg] = lv;
        ((float4*)A2)[rl * 16 + sg] = make_float4(lv.x * xv.x, lv.y * xv.y,
                                                  lv.z * xv.z, lv.w * xv.w);
    }
    __syncthreads();

    const int tx = t & 15;
    const int ty = t >> 4;
    float bs[4];
    {
        float4 bb1 = *(const float4*)&b1[tx * 4];
        float4 bb2 = *(const float4*)&b2[tx * 4];
        bs[0] = bb1.x + bb2.x; bs[1] = bb1.y + bb2.y;
        bs[2] = bb1.z + bb2.z; bs[3] = bb1.w + bb2.w;
    }
    float acc[4][4];
#pragma unroll
    for (int i = 0; i < 4; ++i)
#pragma unroll
        for (int j = 0; j < 4; ++j) acc[i][j] = bs[j];

    for (int k4 = 0; k4 < 16; ++k4) {
        float4 a1[4], a2[4];
#pragma unroll
        for (int i = 0; i < 4; ++i) {
            int r = ty * 4 + i;
            int sg = k4 ^ (r & 15);
            a1[i] = ((const float4*)A1)[r * 16 + sg];
            a2[i] = ((const float4*)A2)[r * 16 + sg];
        }
#pragma unroll
        for (int kk = 0; kk < 4; ++kk) {
            float4 w1 = ((const float4*)Ws1)[(k4 * 4 + kk) * 16 + tx];
            float4 w2 = ((const float4*)Ws2)[(k4 * 4 + kk) * 16 + tx];
#pragma unroll
            for (int i = 0; i < 4; ++i) {
                float av1 = (&a1[i].x)[kk];
                float av2 = (&a2[i].x)[kk];
                acc[i][0] = fmaf(av1, w1.x, fmaf(av2, w2.x, acc[i][0]));
                acc[i][1] = fmaf(av1, w1.y, fmaf(av2, w2.y, acc[i][1]));
                acc[i][2] = fmaf(av1, w1.z, fmaf(av2, w2.z, acc[i][2]));
                acc[i][3] = fmaf(av1, w1.w, fmaf(av2, w2.w, acc[i][3]));
            }
        }
    }
#pragma unroll
    for (int i = 0; i < 4; ++i) {
        int gr = row0 + ty * 4 + i;
        if (gr < NODES) {
            float4 o;
            o.x = acc[i][0] >= 0.f ? acc[i][0] : NEG * acc[i][0];
            o.y = acc[i][1] >= 0.f ? acc[i][1] : NEG * acc[i][1];
            o.z = acc[i][2] >= 0.f ? acc[i][2] : NEG * acc[i][2];
            o.w = acc[i][3] >= 0.f ? acc[i][3] : NEG * acc[i][3];
            *(float4*)&liex[gr * DD + tx * 4] = o;
        }
    }
}

// ---------------------------------------------------------------- gather layer repr into output
__global__ __launch_bounds__(256) void k_gather(const float* __restrict__ x,
                                                const int* __restrict__ su,
                                                const int* __restrict__ oi,
                                                const int* __restrict__ ui,
                                                float* __restrict__ out, int layer) {
    int w    = (blockIdx.x * 256 + threadIdx.x) >> 6;
    int lane = threadIdx.x & 63;
    if (w >= 3 * BB) return;
    int g = w >> 10, b = w & 1023;
    int node = (g == 0) ? su[b] : (NN + ((g == 1) ? oi[b] : ui[b]));
    out[w * 256 + layer * 64 + lane] = x[node * DD + lane];
}

// ---------------------------------------------------------------- launch
extern "C" void kernel_launch(void* const* d_in, const int* in_sizes, int n_in,
                              void* d_out, int out_size, void* d_ws, size_t ws_size,
                              hipStream_t stream) {
    const int*   edge_row = (const int*)d_in[0];
    const int*   edge_col = (const int*)d_in[1];
    const float* edge_val = (const float*)d_in[2];
    const float* eu = (const float*)d_in[3];
    const float* ei = (const float*)d_in[4];
    const float* W1 = (const float*)d_in[5];
    const float* W2 = (const float*)d_in[6];
    const float* b1 = (const float*)d_in[7];
    const float* b2 = (const float*)d_in[8];
    const int*   su = (const int*)d_in[9];
    const int*   oi = (const int*)d_in[10];
    const int*   ui = (const int*)d_in[11];
    float* out = (float*)d_out;

    // workspace carve (~85 MB): xa/xb ping-pong, then sort bufs
    float* xa     = (float*)d_ws;                    // 25.6 MB
    float* xb     = xa + NODES * DD;                 // 25.6 MB
    int2*  bulk   = (int2*)(xb + NODES * DD);        // NBUCK*CAP int2 (28.6 MB)
    int*   gcur   = (int*)(bulk + NBUCK * CAP);      // NBUCK
    int*   starts = gcur + NBUCK + 1;                // NBUCK*SPB (5.2 MB)

    k_init_x<<<(NODES * DD / 4 + 255) / 256, 256, 0, stream>>>(eu, ei, xa, gcur);
    k_gather<<<(3 * BB * 64 + 255) / 256, 256, 0, stream>>>(xa, su, oi, ui, out, 0);

    k_place<<<NPB, 512, 0, stream>>>(edge_row, edge_col, edge_val, gcur, bulk);
    k_csr<<<NBUCK, 512, 0, stream>>>(gcur, bulk, starts);

    const float* xsrc = xa;
    float*       xdst = xb;
    for (int l = 0; l < 3; ++l) {
        if (l == 1) {
            // control arm: R9 pair, adapted to ping-pong (lie lives in xdst)
            k_cspmm<<<NBUCK, 1024, 0, stream>>>(starts, bulk, xsrc, xdst);
            k_gemm_pp<<<(NODES + 63) / 64, 256, 0, stream>>>(xsrc, xdst,
                                                             W1 + l * 4096, W2 + l * 4096,
                                                             b1 + l * 64,  b2 + l * 64);
        } else {
            k_fused<<<NBUCK, 1024, 0, stream>>>(starts, bulk, xsrc, xdst,
                                                W1 + l * 4096, W2 + l * 4096,
                                                b1 + l * 64,  b2 + l * 64);
        }
        k_gather<<<(3 * BB * 64 + 255) / 256, 256, 0, stream>>>(xdst, su, oi, ui,
                                                                out, l + 1);
        const float* tmp = xsrc; xsrc = xdst; xdst = (float*)tmp;
    }
}

// Round 12
// 580.507 us; speedup vs baseline: 2.7848x; 1.0891x over previous
//
#include <hip/hip_runtime.h>

#define NN    60000
#define NODES 100000
#define DD    64
#define NNZ   3200000
#define BB    1024
#define NEG   0.2f
#define RPB   196                        // rows per bucket
#define NBUCK 511                        // ceil(NODES/RPB)
#define EPB   8192                       // edges per sort block
#define NPB   ((NNZ + EPB - 1) / EPB)    // 391
#define CAP   7000                       // bucket capacity (mean 6272, sd~79)
#define BCAP  7168                       // LDS edge capacity in k_csr
#define NSEG  13                         // column segments (col>>13), ~2 MB x-slice each
#define KEYN  (NSEG * RPB)               // 2548 sort keys per bucket
#define SPB   (KEYN + 1)                 // starts entries per bucket
#define ASTR  68                         // padded acc row stride (floats): distinct banks
#define ASTR4 17                         //   for 4-row epilogue reads; 272 B keeps b128 align

// ---------------------------------------------------------------- init xa = concat(eu, ei); also init gcur
__global__ __launch_bounds__(256) void k_init_x(const float* __restrict__ eu,
                                                const float* __restrict__ ei,
                                                float* __restrict__ x,
                                                int* __restrict__ gcur) {
    int i = blockIdx.x * 256 + threadIdx.x;          // float4 index
    if (i < NBUCK) gcur[i] = i * CAP;
    const int TOT = NODES * DD / 4;
    if (i >= TOT) return;
    const int UE = NN * DD / 4;
    float4 v = (i < UE) ? ((const float4*)eu)[i] : ((const float4*)ei)[i - UE];
    ((float4*)x)[i] = v;
}

// ---------------------------------------------------------------- bucket sort -> bulk
__global__ __launch_bounds__(512) void k_place(const int* __restrict__ row,
                                               const int* __restrict__ col,
                                               const float* __restrict__ val,
                                               int* __restrict__ gcur,
                                               int2* __restrict__ bulk) {
    __shared__ int rows_l[EPB];                // 32 KB
    __shared__ unsigned short perm[EPB];       // 16 KB
    __shared__ int h[NBUCK], bloc[NBUCK], bcur[NBUCK], gseg[NBUCK];
    __shared__ int sc[512];
    int t = threadIdx.x;
    if (t < NBUCK) h[t] = 0;
    __syncthreads();
    int base = blockIdx.x * EPB;
    int n = min(EPB, NNZ - base);
    for (int k = t; k < n; k += 512) {
        int r = row[base + k];
        rows_l[k] = r;
        atomicAdd(&h[r / RPB], 1);
    }
    __syncthreads();
    {
        int v = (t < NBUCK) ? h[t] : 0;
        sc[t] = v;
        __syncthreads();
        for (int off = 1; off < 512; off <<= 1) {
            int u = (t >= off) ? sc[t - off] : 0;
            __syncthreads();
            sc[t] += u;
            __syncthreads();
        }
        if (t < NBUCK) {
            int ex = sc[t] - v;
            bloc[t] = ex;
            bcur[t] = ex;
            gseg[t] = v ? atomicAdd(&gcur[t], v) : 0;
        }
    }
    __syncthreads();
    for (int k = t; k < n; k += 512) {
        int p = atomicAdd(&bcur[rows_l[k] / RPB], 1);
        perm[p] = (unsigned short)k;
    }
    __syncthreads();
    for (int j = t; j < n; j += 512) {
        int k = perm[j];
        int r = rows_l[k];
        int b = r / RPB;
        int addr = gseg[b] + (j - bloc[b]);
        bulk[addr] = make_int2(((r - b * RPB) << 17) | col[base + k],
                               __float_as_int(val[base + k]));
    }
}

// ---------------------------------------------------------------- per-bucket (colseg,row) sort
// in-place (keeps packed local-row bits); emit per-key span starts + sentinel
__global__ __launch_bounds__(512) void k_csr(const int* __restrict__ gcur,
                                             int2* __restrict__ bulk,
                                             int* __restrict__ starts) {
    __shared__ int2 eds[BCAP];                 // 56 KB
    __shared__ int cnt[KEYN], pos[KEYN];       // 20 KB
    __shared__ int part[512];
    int b = blockIdx.x, t = threadIdx.x;
    int lo = b * CAP;
    int n = gcur[b] - lo;
    for (int k = t; k < KEYN; k += 512) cnt[k] = 0;
    __syncthreads();
    for (int i = t; i < n; i += 512) {
        int2 ed = bulk[lo + i];
        eds[i] = ed;
        int lr = ed.x >> 17, c = ed.x & 0x1FFFF;
        atomicAdd(&cnt[(c >> 13) * RPB + lr], 1);
    }
    __syncthreads();
    // two-level exclusive scan over KEYN bins (5 bins/thread)
    int run = 0;
#pragma unroll
    for (int j = 0; j < 5; ++j) {
        int k = t * 5 + j;
        if (k < KEYN) { pos[k] = run; run += cnt[k]; }
    }
    part[t] = run;
    __syncthreads();
    for (int off = 1; off < 512; off <<= 1) {
        int u = (t >= off) ? part[t - off] : 0;
        __syncthreads();
        part[t] += u;
        __syncthreads();
    }
    int poff = part[t] - run;
#pragma unroll
    for (int j = 0; j < 5; ++j) {
        int k = t * 5 + j;
        if (k < KEYN) pos[k] += poff;
    }
    __syncthreads();
    for (int k = t; k < KEYN; k += 512) {
        starts[b * SPB + k] = lo + pos[k];
        cnt[k] = pos[k];                      // reuse as cursor
    }
    if (t == 0) starts[b * SPB + KEYN] = lo + n;
    __syncthreads();
    for (int i = t; i < n; i += 512) {
        int2 ed = eds[i];
        int lr = ed.x >> 17, c = ed.x & 0x1FFFF;
        int p = atomicAdd(&cnt[(c >> 13) * RPB + lr], 1);
        bulk[lo + p] = ed;                    // keep packed (lr<<17 | col)
    }
}

// ---------------------------------------------------------------- SpMM core macros (R9 PIPE1, measured ~83 us)
#define SPMM_BODY(XSRC, ACCDST)                                                  \
    for (int seg = 0; seg < NSEG; ++seg) {                                       \
        int s = starts[sb + seg * RPB + r0];                                     \
        int e = starts[sb + seg * RPB + r1];                                     \
        int cur = -1;                                                            \
        float f = 0.f;                                                           \
        int2 emA[8], emB[8];                                                     \
        float xwA[8], xwB[8];                                                    \
        int nb = (e - s) >> 3;                                                   \
        if (nb > 0) {                                                            \
            LDM(A, s) GTH(A, XSRC)                                               \
            int ld = 1;                                                          \
            for (;;) {                                                           \
                if (ld < nb) { LDM(B, s + ld * 8) GTH(B, XSRC) ++ld; CNS(A, ACCDST) } \
                else         { CNS(A, ACCDST) break; }                           \
                if (ld < nb) { LDM(A, s + ld * 8) GTH(A, XSRC) ++ld; CNS(B, ACCDST) } \
                else         { CNS(B, ACCDST) break; }                           \
            }                                                                    \
        }                                                                        \
        for (int g = s + nb * 8; g < e; ++g) {                                   \
            int2 ed = cv[g];                                                     \
            float xg = XSRC[(ed.x & 0x1FFFF) * DD + lane];                       \
            int r = ed.x >> 17;                                                  \
            if (r != cur) {                                                      \
                if (cur >= 0) ACCDST[cur * ASTR + lane] += f;                    \
                cur = r; f = 0.f;                                                \
            }                                                                    \
            f = fmaf(__int_as_float(ed.y), xg, f);                               \
        }                                                                        \
        if (cur >= 0) ACCDST[cur * ASTR + lane] += f;                            \
    }
#define LDM(S, gg) { _Pragma("unroll") \
    for (int j = 0; j < 8; ++j) em##S[j] = cv[(gg) + j]; }
#define GTH(S, XSRC) { _Pragma("unroll") \
    for (int j = 0; j < 8; ++j) xw##S[j] = XSRC[(em##S[j].x & 0x1FFFF) * DD + lane]; }
#define CNS(S, ACCDST) { _Pragma("unroll") \
    for (int j = 0; j < 8; ++j) { \
        int r = em##S[j].x >> 17; \
        if (r != cur) { if (cur >= 0) ACCDST[cur * ASTR + lane] += f; cur = r; f = 0.f; } \
        f = fmaf(__int_as_float(em##S[j].y), xw##S[j], f); } }

// ---------------------------------------------------------------- fused SpMM + layer GEMM (v2)
// R11 failure: 1-row epilogue had zero weight amortization (~6400 weight VMEM
// wave-instrs/block, latency-exposed) + acc bank aliasing (stride 64 = 0 mod
// 32 banks, 1.6M conflict cycles). v2: k_gemm-shaped 4 rows x 4 cols per
// thread (weights serve 16 outputs -> ~2050 weight instrs), acc padded to
// stride 68 (distinct banks, b128-aligned), k4 loop pinned at unroll 1
// (R10: default unroll -> 64-VGPR blowout), __launch_bounds__(1024,8) pins
// the allocator at the 64-VGPR / 2-blocks-per-CU cliff edge.
__global__ __launch_bounds__(1024, 8) void k_fused(const int* __restrict__ starts,
                                                   const int2* __restrict__ cv,
                                                   const float* __restrict__ xs,
                                                   float* __restrict__ xd,
                                                   const float* __restrict__ W1,
                                                   const float* __restrict__ W2,
                                                   const float* __restrict__ b1,
                                                   const float* __restrict__ b2) {
    __shared__ float acc[RPB * ASTR];          // 53312 B -> still 2 blocks/CU
    int t = threadIdx.x, b = blockIdx.x;
    float4* av = (float4*)acc;
    for (int i = t; i < RPB * ASTR4; i += 1024) av[i] = make_float4(0.f, 0.f, 0.f, 0.f);
    __syncthreads();
    int lane = t & 63;
    int wid = __builtin_amdgcn_readfirstlane(t >> 6);   // provably wave-uniform
    int r0 = (wid * RPB) >> 4;
    int r1 = ((wid + 1) * RPB) >> 4;
    int sb = b * SPB;
    SPMM_BODY(xs, acc)
    __syncthreads();

    // ---------------- fused GEMM epilogue: 4 rows x 4 cols per thread ----------------
    {
        const int row0 = b * RPB;
        const int tx = t & 15;                 // col group (4 cols)
        const int ty = t >> 4;                 // 0..63; ty<49 active (49*4=196 rows)
        if (ty < 49) {
            const float4* w1v = (const float4*)W1;
            const float4* w2v = (const float4*)W2;
            float4 b1v = ((const float4*)b1)[tx];
            float4 b2v = ((const float4*)b2)[tx];
            float4 o[4];
#pragma unroll
            for (int i = 0; i < 4; ++i)
                o[i] = make_float4(b1v.x + b2v.x, b1v.y + b2v.y,
                                   b1v.z + b2v.z, b1v.w + b2v.w);
            const int lr0 = ty * 4;
#pragma unroll 1
            for (int k4 = 0; k4 < 16; ++k4) {
                float4 a1[4], x4[4];
#pragma unroll
                for (int i = 0; i < 4; ++i) {
                    a1[i] = *(const float4*)&acc[(lr0 + i) * ASTR + k4 * 4];
                    int gr = row0 + lr0 + i;
                    x4[i] = ((const float4*)xs)[(gr < NODES ? gr : 0) * 16 + k4];
                }
#pragma unroll
                for (int kk = 0; kk < 4; ++kk) {
                    float4 w1r = w1v[(k4 * 4 + kk) * 16 + tx];
                    float4 w2r = w2v[(k4 * 4 + kk) * 16 + tx];
#pragma unroll
                    for (int i = 0; i < 4; ++i) {
                        float lk = (&a1[i].x)[kk];
                        float ak = lk * (&x4[i].x)[kk];
                        o[i].x = fmaf(lk, w1r.x, fmaf(ak, w2r.x, o[i].x));
                        o[i].y = fmaf(lk, w1r.y, fmaf(ak, w2r.y, o[i].y));
                        o[i].z = fmaf(lk, w1r.z, fmaf(ak, w2r.z, o[i].z));
                        o[i].w = fmaf(lk, w1r.w, fmaf(ak, w2r.w, o[i].w));
                    }
                }
            }
#pragma unroll
            for (int i = 0; i < 4; ++i) {
                int gr = row0 + lr0 + i;
                if (gr < NODES) {
                    float4 v = o[i];
                    v.x = v.x >= 0.f ? v.x : NEG * v.x;
                    v.y = v.y >= 0.f ? v.y : NEG * v.y;
                    v.z = v.z >= 0.f ? v.z : NEG * v.z;
                    v.w = v.w >= 0.f ? v.w : NEG * v.w;
                    ((float4*)xd)[gr * 16 + tx] = v;
                }
            }
        }
    }
}

// ---------------------------------------------------------------- unfused SpMM (R9 PIPE1) -- control arm
__global__ __launch_bounds__(1024) void k_cspmm(const int* __restrict__ starts,
                                                const int2* __restrict__ cv,
                                                const float* __restrict__ xs,
                                                float* __restrict__ lie) {
    __shared__ float acc[RPB * ASTR];          // padded like k_fused
    int t = threadIdx.x, b = blockIdx.x;
    float4* av = (float4*)acc;
    for (int i = t; i < RPB * ASTR4; i += 1024) av[i] = make_float4(0.f, 0.f, 0.f, 0.f);
    __syncthreads();
    int lane = t & 63;
    int wid = __builtin_amdgcn_readfirstlane(t >> 6);
    int r0 = (wid * RPB) >> 4;
    int r1 = ((wid + 1) * RPB) >> 4;
    int sb = b * SPB;
    SPMM_BODY(xs, acc)
    __syncthreads();
    int row0 = b * RPB;
    for (int i = t; i < RPB * 16; i += 1024) {
        int gr = row0 + (i >> 4);
        if (gr < NODES) ((float4*)lie)[gr * 16 + (i & 15)] = av[(i >> 4) * ASTR4 + (i & 15)];
    }
}
#undef LDM
#undef GTH
#undef CNS
#undef SPMM_BODY

// ---------------------------------------------------------------- layer GEMM, ping-pong variant (control)
__global__ __launch_bounds__(256) void k_gemm_pp(const float* __restrict__ x_in,
                                                 float* __restrict__ liex,
                                                 const float* __restrict__ W1,
                                                 const float* __restrict__ W2,
                                                 const float* __restrict__ b1,
                                                 const float* __restrict__ b2) {
    __shared__ float A1[64 * 64];
    __shared__ float A2[64 * 64];
    __shared__ float Ws1[64 * 64];
    __shared__ float Ws2[64 * 64];

    const int t = threadIdx.x;
    const int row0 = blockIdx.x * 64;

    {
        const float4* w1v = (const float4*)W1;
        const float4* w2v = (const float4*)W2;
        float4* s1v = (float4*)Ws1;
        float4* s2v = (float4*)Ws2;
#pragma unroll
        for (int q = 0; q < 4; ++q) {
            s1v[q * 256 + t] = w1v[q * 256 + t];
            s2v[q * 256 + t] = w2v[q * 256 + t];
        }
    }
#pragma unroll
    for (int q = 0; q < 4; ++q) {
        int f4 = q * 256 + t;
        int rl = f4 >> 4;
        int c4 = f4 & 15;
        int gr = row0 + rl;
        float4 lv = make_float4(0.f, 0.f, 0.f, 0.f);
        float4 xv = make_float4(0.f, 0.f, 0.f, 0.f);
        if (gr < NODES) {
            lv = *(const float4*)&liex[gr * DD + c4 * 4];
            xv = *(const float4*)&x_in[gr * DD + c4 * 4];
        }
        int sg = c4 ^ (rl & 15);
        ((float4*)A1)[rl * 16 + sg] = lv;
        ((float4*)A2)[rl * 16 + sg] = make_float4(lv.x * xv.x, lv.y * xv.y,
                                                  lv.z * xv.z, lv.w * xv.w);
    }
    __syncthreads();

    const int tx = t & 15;
    const int ty = t >> 4;
    float bs[4];
    {
        float4 bb1 = *(const float4*)&b1[tx * 4];
        float4 bb2 = *(const float4*)&b2[tx * 4];
        bs[0] = bb1.x + bb2.x; bs[1] = bb1.y + bb2.y;
        bs[2] = bb1.z + bb2.z; bs[3] = bb1.w + bb2.w;
    }
    float acc[4][4];
#pragma unroll
    for (int i = 0; i < 4; ++i)
#pragma unroll
        for (int j = 0; j < 4; ++j) acc[i][j] = bs[j];

    for (int k4 = 0; k4 < 16; ++k4) {
        float4 a1[4], a2[4];
#pragma unroll
        for (int i = 0; i < 4; ++i) {
            int r = ty * 4 + i;
            int sg = k4 ^ (r & 15);
            a1[i] = ((const float4*)A1)[r * 16 + sg];
            a2[i] = ((const float4*)A2)[r * 16 + sg];
        }
#pragma unroll
        for (int kk = 0; kk < 4; ++kk) {
            float4 w1 = ((const float4*)Ws1)[(k4 * 4 + kk) * 16 + tx];
            float4 w2 = ((const float4*)Ws2)[(k4 * 4 + kk) * 16 + tx];
#pragma unroll
            for (int i = 0; i < 4; ++i) {
                float av1 = (&a1[i].x)[kk];
                float av2 = (&a2[i].x)[kk];
                acc[i][0] = fmaf(av1, w1.x, fmaf(av2, w2.x, acc[i][0]));
                acc[i][1] = fmaf(av1, w1.y, fmaf(av2, w2.y, acc[i][1]));
                acc[i][2] = fmaf(av1, w1.z, fmaf(av2, w2.z, acc[i][2]));
                acc[i][3] = fmaf(av1, w1.w, fmaf(av2, w2.w, acc[i][3]));
            }
        }
    }
#pragma unroll
    for (int i = 0; i < 4; ++i) {
        int gr = row0 + ty * 4 + i;
        if (gr < NODES) {
            float4 o;
            o.x = acc[i][0] >= 0.f ? acc[i][0] : NEG * acc[i][0];
            o.y = acc[i][1] >= 0.f ? acc[i][1] : NEG * acc[i][1];
            o.z = acc[i][2] >= 0.f ? acc[i][2] : NEG * acc[i][2];
            o.w = acc[i][3] >= 0.f ? acc[i][3] : NEG * acc[i][3];
            *(float4*)&liex[gr * DD + tx * 4] = o;
        }
    }
}

// ---------------------------------------------------------------- gather layer repr into output
__global__ __launch_bounds__(256) void k_gather(const float* __restrict__ x,
                                                const int* __restrict__ su,
                                                const int* __restrict__ oi,
                                                const int* __restrict__ ui,
                                                float* __restrict__ out, int layer) {
    int w    = (blockIdx.x * 256 + threadIdx.x) >> 6;
    int lane = threadIdx.x & 63;
    if (w >= 3 * BB) return;
    int g = w >> 10, b = w & 1023;
    int node = (g == 0) ? su[b] : (NN + ((g == 1) ? oi[b] : ui[b]));
    out[w * 256 + layer * 64 + lane] = x[node * DD + lane];
}

// ---------------------------------------------------------------- launch
extern "C" void kernel_launch(void* const* d_in, const int* in_sizes, int n_in,
                              void* d_out, int out_size, void* d_ws, size_t ws_size,
                              hipStream_t stream) {
    const int*   edge_row = (const int*)d_in[0];
    const int*   edge_col = (const int*)d_in[1];
    const float* edge_val = (const float*)d_in[2];
    const float* eu = (const float*)d_in[3];
    const float* ei = (const float*)d_in[4];
    const float* W1 = (const float*)d_in[5];
    const float* W2 = (const float*)d_in[6];
    const float* b1 = (const float*)d_in[7];
    const float* b2 = (const float*)d_in[8];
    const int*   su = (const int*)d_in[9];
    const int*   oi = (const int*)d_in[10];
    const int*   ui = (const int*)d_in[11];
    float* out = (float*)d_out;

    // workspace carve (~85 MB): xa/xb ping-pong, then sort bufs
    float* xa     = (float*)d_ws;                    // 25.6 MB
    float* xb     = xa + NODES * DD;                 // 25.6 MB
    int2*  bulk   = (int2*)(xb + NODES * DD);        // NBUCK*CAP int2 (28.6 MB)
    int*   gcur   = (int*)(bulk + NBUCK * CAP);      // NBUCK
    int*   starts = gcur + NBUCK + 1;                // NBUCK*SPB (5.2 MB)

    k_init_x<<<(NODES * DD / 4 + 255) / 256, 256, 0, stream>>>(eu, ei, xa, gcur);
    k_gather<<<(3 * BB * 64 + 255) / 256, 256, 0, stream>>>(xa, su, oi, ui, out, 0);

    k_place<<<NPB, 512, 0, stream>>>(edge_row, edge_col, edge_val, gcur, bulk);
    k_csr<<<NBUCK, 512, 0, stream>>>(gcur, bulk, starts);

    const float* xsrc = xa;
    float*       xdst = xb;
    for (int l = 0; l < 3; ++l) {
        if (l == 1) {
            // control arm: split pair (lie lives in xdst, GEMM rewrites in place)
            k_cspmm<<<NBUCK, 1024, 0, stream>>>(starts, bulk, xsrc, xdst);
            k_gemm_pp<<<(NODES + 63) / 64, 256, 0, stream>>>(xsrc, xdst,
                                                             W1 + l * 4096, W2 + l * 4096,
                                                             b1 + l * 64,  b2 + l * 64);
        } else {
            k_fused<<<NBUCK, 1024, 0, stream>>>(starts, bulk, xsrc, xdst,
                                                W1 + l * 4096, W2 + l * 4096,
                                                b1 + l * 64,  b2 + l * 64);
        }
        k_gather<<<(3 * BB * 64 + 255) / 256, 256, 0, stream>>>(xdst, su, oi, ui,
                                                                out, l + 1);
        const float* tmp = xsrc; xsrc = xdst; xdst = (float*)tmp;
    }
}

// Round 14
// 523.758 us; speedup vs baseline: 3.0866x; 1.1083x over previous
//
#include <hip/hip_runtime.h>

#define NN    60000
#define NODES 100000
#define DD    64
#define NNZ   3200000
#define BB    1024
#define NEG   0.2f
#define RPB   196                        // rows per bucket
#define NBUCK 511                        // ceil(NODES/RPB)
#define EPB   8192                       // edges per sort block
#define NPB   ((NNZ + EPB - 1) / EPB)    // 391
#define CAP   7000                       // bucket capacity (mean 6272, sd~79)
#define BCAP  7168                       // LDS edge capacity in k_csr
#define NSEG  13                         // column segments (col>>13), ~2 MB x-slice each
#define KEYN  (NSEG * RPB)               // 2548 sort keys per bucket
#define SPB   (KEYN + 1)                 // starts entries per bucket

// ---------------------------------------------------------------- init x = concat(eu, ei); also init gcur
__global__ __launch_bounds__(256) void k_init_x(const float* __restrict__ eu,
                                                const float* __restrict__ ei,
                                                float* __restrict__ x,
                                                int* __restrict__ gcur) {
    int i = blockIdx.x * 256 + threadIdx.x;          // float4 index
    if (i < NBUCK) gcur[i] = i * CAP;
    const int TOT = NODES * DD / 4;
    if (i >= TOT) return;
    const int UE = NN * DD / 4;
    float4 v = (i < UE) ? ((const float4*)eu)[i] : ((const float4*)ei)[i - UE];
    ((float4*)x)[i] = v;
}

// ---------------------------------------------------------------- bucket sort -> bulk
__global__ __launch_bounds__(512) void k_place(const int* __restrict__ row,
                                               const int* __restrict__ col,
                                               const float* __restrict__ val,
                                               int* __restrict__ gcur,
                                               int2* __restrict__ bulk) {
    __shared__ int rows_l[EPB];                // 32 KB
    __shared__ unsigned short perm[EPB];       // 16 KB
    __shared__ int h[NBUCK], bloc[NBUCK], bcur[NBUCK], gseg[NBUCK];
    __shared__ int sc[512];
    int t = threadIdx.x;
    if (t < NBUCK) h[t] = 0;
    __syncthreads();
    int base = blockIdx.x * EPB;
    int n = min(EPB, NNZ - base);
    for (int k = t; k < n; k += 512) {
        int r = row[base + k];
        rows_l[k] = r;
        atomicAdd(&h[r / RPB], 1);
    }
    __syncthreads();
    {
        int v = (t < NBUCK) ? h[t] : 0;
        sc[t] = v;
        __syncthreads();
        for (int off = 1; off < 512; off <<= 1) {
            int u = (t >= off) ? sc[t - off] : 0;
            __syncthreads();
            sc[t] += u;
            __syncthreads();
        }
        if (t < NBUCK) {
            int ex = sc[t] - v;
            bloc[t] = ex;
            bcur[t] = ex;
            gseg[t] = v ? atomicAdd(&gcur[t], v) : 0;
        }
    }
    __syncthreads();
    for (int k = t; k < n; k += 512) {
        int p = atomicAdd(&bcur[rows_l[k] / RPB], 1);
        perm[p] = (unsigned short)k;
    }
    __syncthreads();
    for (int j = t; j < n; j += 512) {
        int k = perm[j];
        int r = rows_l[k];
        int b = r / RPB;
        int addr = gseg[b] + (j - bloc[b]);
        bulk[addr] = make_int2(((r - b * RPB) << 17) | col[base + k],
                               __float_as_int(val[base + k]));
    }
}

// ---------------------------------------------------------------- per-bucket (colseg,row) sort
// in-place (keeps packed local-row bits); emit per-key span starts + sentinel
__global__ __launch_bounds__(512) void k_csr(const int* __restrict__ gcur,
                                             int2* __restrict__ bulk,
                                             int* __restrict__ starts) {
    __shared__ int2 eds[BCAP];                 // 56 KB
    __shared__ int cnt[KEYN], pos[KEYN];       // 20 KB
    __shared__ int part[512];
    int b = blockIdx.x, t = threadIdx.x;
    int lo = b * CAP;
    int n = gcur[b] - lo;
    for (int k = t; k < KEYN; k += 512) cnt[k] = 0;
    __syncthreads();
    for (int i = t; i < n; i += 512) {
        int2 ed = bulk[lo + i];
        eds[i] = ed;
        int lr = ed.x >> 17, c = ed.x & 0x1FFFF;
        atomicAdd(&cnt[(c >> 13) * RPB + lr], 1);
    }
    __syncthreads();
    // two-level exclusive scan over KEYN bins (5 bins/thread)
    int run = 0;
#pragma unroll
    for (int j = 0; j < 5; ++j) {
        int k = t * 5 + j;
        if (k < KEYN) { pos[k] = run; run += cnt[k]; }
    }
    part[t] = run;
    __syncthreads();
    for (int off = 1; off < 512; off <<= 1) {
        int u = (t >= off) ? part[t - off] : 0;
        __syncthreads();
        part[t] += u;
        __syncthreads();
    }
    int poff = part[t] - run;
#pragma unroll
    for (int j = 0; j < 5; ++j) {
        int k = t * 5 + j;
        if (k < KEYN) pos[k] += poff;
    }
    __syncthreads();
    for (int k = t; k < KEYN; k += 512) {
        starts[b * SPB + k] = lo + pos[k];
        cnt[k] = pos[k];                      // reuse as cursor
    }
    if (t == 0) starts[b * SPB + KEYN] = lo + n;
    __syncthreads();
    for (int i = t; i < n; i += 512) {
        int2 ed = eds[i];
        int lr = ed.x >> 17, c = ed.x & 0x1FFFF;
        int p = atomicAdd(&cnt[(c >> 13) * RPB + lr], 1);
        bulk[lo + p] = ed;                    // keep packed (lr<<17 | col)
    }
}

// ---------------------------------------------------------------- convoyed seg-major pull SpMM
// TAIL 0 = exact R9 PIPE1 (measured 83.9-84.2 us, the session's verified best):
//   readfirstlane(wid) -> scalar loop control; meta via s_load (lgkmcnt),
//   gathers via vmcnt; 2-deep split-counter pipeline; serial tail.
// TAIL 1 = same, but the <=7-edge serial tail is replaced by ONE clamped
//   8-deep block: idx clamps to e-1 (scalar ternary -> stays s_load), pad
//   lanes fma 0 (duplicate row -> r==cur -> no spurious flush). The ~6
//   serially-chained tail edges (~350cy each) become one pipelined block.
template <int TAIL>
__global__ __launch_bounds__(1024) void k_cspmm(const int* __restrict__ starts,
                                                const int2* __restrict__ cv,
                                                const float* __restrict__ x,
                                                float* __restrict__ lie) {
    __shared__ float acc[RPB * DD];            // 49 KB
    int t = threadIdx.x, b = blockIdx.x;
    float4* av = (float4*)acc;
    for (int i = t; i < RPB * 16; i += 1024) av[i] = make_float4(0.f, 0.f, 0.f, 0.f);
    __syncthreads();
    int lane = t & 63;
    int wid = __builtin_amdgcn_readfirstlane(t >> 6);   // provably wave-uniform
    int r0 = (wid * RPB) >> 4;
    int r1 = ((wid + 1) * RPB) >> 4;
    int sb = b * SPB;
    for (int seg = 0; seg < NSEG; ++seg) {
        int s = starts[sb + seg * RPB + r0];
        int e = starts[sb + seg * RPB + r1];   // r1==RPB -> next seg's r0 / sentinel
        int cur = -1;
        float f = 0.f;
        int2 emA[8], emB[8];
        float xwA[8], xwB[8];
#define LDM(S, gg) { _Pragma("unroll") \
    for (int j = 0; j < 8; ++j) em##S[j] = cv[(gg) + j]; }
#define GTH(S) { _Pragma("unroll") \
    for (int j = 0; j < 8; ++j) xw##S[j] = x[(em##S[j].x & 0x1FFFF) * DD + lane]; }
#define CNS(S) { _Pragma("unroll") \
    for (int j = 0; j < 8; ++j) { \
        int r = em##S[j].x >> 17; \
        if (r != cur) { if (cur >= 0) acc[cur * DD + lane] += f; cur = r; f = 0.f; } \
        f = fmaf(__int_as_float(em##S[j].y), xw##S[j], f); } }
        int nb = (e - s) >> 3;                 // full 8-blocks (uniform)
        if (nb > 0) {
            LDM(A, s) GTH(A)
            int ld = 1;
            for (;;) {
                if (ld < nb) { LDM(B, s + ld * 8) GTH(B) ++ld; CNS(A) }
                else         { CNS(A) break; }
                if (ld < nb) { LDM(A, s + ld * 8) GTH(A) ++ld; CNS(B) }
                else         { CNS(B) break; }
            }
        }
#undef LDM
#undef GTH
#undef CNS
        int gt = s + nb * 8;
        if constexpr (TAIL == 0) {
            for (int g = gt; g < e; ++g) {
                int2 ed = cv[g];
                float xg = x[(ed.x & 0x1FFFF) * DD + lane];
                int r = ed.x >> 17;
                if (r != cur) {
                    if (cur >= 0) acc[cur * DD + lane] += f;
                    cur = r; f = 0.f;
                }
                f = fmaf(__int_as_float(ed.y), xg, f);
            }
        } else {
            if (gt < e) {
                int2 em[8];
                float xw[8];
#pragma unroll
                for (int j = 0; j < 8; ++j) {
                    int idx = gt + j;
                    int ic = idx < e ? idx : e - 1;     // scalar clamp
                    em[j] = cv[ic];                     // s_load
                }
#pragma unroll
                for (int j = 0; j < 8; ++j) xw[j] = x[(em[j].x & 0x1FFFF) * DD + lane];
#pragma unroll
                for (int j = 0; j < 8; ++j) {
                    int r = em[j].x >> 17;
                    if (r != cur) {                     // uniform; pads: r==cur
                        if (cur >= 0) acc[cur * DD + lane] += f;
                        cur = r; f = 0.f;
                    }
                    float vv = (gt + j < e) ? __int_as_float(em[j].y) : 0.f;
                    f = fmaf(vv, xw[j], f);
                }
            }
        }
        if (cur >= 0) acc[cur * DD + lane] += f;
    }
    __syncthreads();
    int row0 = b * RPB;
    for (int i = t; i < RPB * 16; i += 1024) {
        int gr = row0 + (i >> 4);
        if (gr < NODES) ((float4*)lie)[gr * 16 + (i & 15)] = av[i];
    }
}

// ---------------------------------------------------------------- fused layer GEMM (R9 original)
__global__ __launch_bounds__(256) void k_gemm(float* __restrict__ x,
                                              const float* __restrict__ lie,
                                              const float* __restrict__ W1,
                                              const float* __restrict__ W2,
                                              const float* __restrict__ b1,
                                              const float* __restrict__ b2) {
    __shared__ float A1[64 * 64];
    __shared__ float A2[64 * 64];
    __shared__ float Ws1[64 * 64];
    __shared__ float Ws2[64 * 64];

    const int t = threadIdx.x;
    const int row0 = blockIdx.x * 64;

    {
        const float4* w1v = (const float4*)W1;
        const float4* w2v = (const float4*)W2;
        float4* s1v = (float4*)Ws1;
        float4* s2v = (float4*)Ws2;
#pragma unroll
        for (int q = 0; q < 4; ++q) {
            s1v[q * 256 + t] = w1v[q * 256 + t];
            s2v[q * 256 + t] = w2v[q * 256 + t];
        }
    }
#pragma unroll
    for (int q = 0; q < 4; ++q) {
        int f4 = q * 256 + t;
        int rl = f4 >> 4;
        int c4 = f4 & 15;
        int gr = row0 + rl;
        float4 lv = make_float4(0.f, 0.f, 0.f, 0.f);
        float4 xv = make_float4(0.f, 0.f, 0.f, 0.f);
        if (gr < NODES) {
            lv = *(const float4*)&lie[gr * DD + c4 * 4];
            xv = *(const float4*)&x[gr * DD + c4 * 4];
        }
        int sg = c4 ^ (rl & 15);
        ((float4*)A1)[rl * 16 + sg] = lv;
        ((float4*)A2)[rl * 16 + sg] = make_float4(lv.x * xv.x, lv.y * xv.y,
                                                  lv.z * xv.z, lv.w * xv.w);
    }
    __syncthreads();

    const int tx = t & 15;
    const int ty = t >> 4;
    float bs[4];
    {
        float4 bb1 = *(const float4*)&b1[tx * 4];
        float4 bb2 = *(const float4*)&b2[tx * 4];
        bs[0] = bb1.x + bb2.x; bs[1] = bb1.y + bb2.y;
        bs[2] = bb1.z + bb2.z; bs[3] = bb1.w + bb2.w;
    }
    float acc[4][4];
#pragma unroll
    for (int i = 0; i < 4; ++i)
#pragma unroll
        for (int j = 0; j < 4; ++j) acc[i][j] = bs[j];

    for (int k4 = 0; k4 < 16; ++k4) {
        float4 a1[4], a2[4];
#pragma unroll
        for (int i = 0; i < 4; ++i) {
            int r = ty * 4 + i;
            int sg = k4 ^ (r & 15);
            a1[i] = ((const float4*)A1)[r * 16 + sg];
            a2[i] = ((const float4*)A2)[r * 16 + sg];
        }
#pragma unroll
        for (int kk = 0; kk < 4; ++kk) {
            float4 w1 = ((const float4*)Ws1)[(k4 * 4 + kk) * 16 + tx];
            float4 w2 = ((const float4*)Ws2)[(k4 * 4 + kk) * 16 + tx];
#pragma unroll
            for (int i = 0; i < 4; ++i) {
                float av1 = (&a1[i].x)[kk];
                float av2 = (&a2[i].x)[kk];
                acc[i][0] = fmaf(av1, w1.x, fmaf(av2, w2.x, acc[i][0]));
                acc[i][1] = fmaf(av1, w1.y, fmaf(av2, w2.y, acc[i][1]));
                acc[i][2] = fmaf(av1, w1.z, fmaf(av2, w2.z, acc[i][2]));
                acc[i][3] = fmaf(av1, w1.w, fmaf(av2, w2.w, acc[i][3]));
            }
        }
    }
#pragma unroll
    for (int i = 0; i < 4; ++i) {
        int gr = row0 + ty * 4 + i;
        if (gr < NODES) {
            float4 o;
            o.x = acc[i][0] >= 0.f ? acc[i][0] : NEG * acc[i][0];
            o.y = acc[i][1] >= 0.f ? acc[i][1] : NEG * acc[i][1];
            o.z = acc[i][2] >= 0.f ? acc[i][2] : NEG * acc[i][2];
            o.w = acc[i][3] >= 0.f ? acc[i][3] : NEG * acc[i][3];
            *(float4*)&x[gr * DD + tx * 4] = o;
        }
    }
}

// ---------------------------------------------------------------- gather layer repr into output
__global__ __launch_bounds__(256) void k_gather(const float* __restrict__ x,
                                                const int* __restrict__ su,
                                                const int* __restrict__ oi,
                                                const int* __restrict__ ui,
                                                float* __restrict__ out, int layer) {
    int w    = (blockIdx.x * 256 + threadIdx.x) >> 6;
    int lane = threadIdx.x & 63;
    if (w >= 3 * BB) return;
    int g = w >> 10, b = w & 1023;
    int node = (g == 0) ? su[b] : (NN + ((g == 1) ? oi[b] : ui[b]));
    out[w * 256 + layer * 64 + lane] = x[node * DD + lane];
}

// ---------------------------------------------------------------- launch (exact R9 structure)
extern "C" void kernel_launch(void* const* d_in, const int* in_sizes, int n_in,
                              void* d_out, int out_size, void* d_ws, size_t ws_size,
                              hipStream_t stream) {
    const int*   edge_row = (const int*)d_in[0];
    const int*   edge_col = (const int*)d_in[1];
    const float* edge_val = (const float*)d_in[2];
    const float* eu = (const float*)d_in[3];
    const float* ei = (const float*)d_in[4];
    const float* W1 = (const float*)d_in[5];
    const float* W2 = (const float*)d_in[6];
    const float* b1 = (const float*)d_in[7];
    const float* b2 = (const float*)d_in[8];
    const int*   su = (const int*)d_in[9];
    const int*   oi = (const int*)d_in[10];
    const int*   ui = (const int*)d_in[11];
    float* out = (float*)d_out;

    // workspace carve (~85 MB)
    float* x      = (float*)d_ws;                    // 25.6 MB
    float* lie    = x + NODES * DD;                  // 25.6 MB
    int2*  bulk   = (int2*)(lie + NODES * DD);       // NBUCK*CAP int2 (28.6 MB)
    int*   gcur   = (int*)(bulk + NBUCK * CAP);      // NBUCK
    int*   starts = gcur + NBUCK + 1;                // NBUCK*SPB (5.2 MB)

    k_init_x<<<(NODES * DD / 4 + 255) / 256, 256, 0, stream>>>(eu, ei, x, gcur);
    k_gather<<<(3 * BB * 64 + 255) / 256, 256, 0, stream>>>(x, su, oi, ui, out, 0);

    k_place<<<NPB, 512, 0, stream>>>(edge_row, edge_col, edge_val, gcur, bulk);
    k_csr<<<NBUCK, 512, 0, stream>>>(gcur, bulk, starts);

    for (int l = 0; l < 3; ++l) {
        if (l == 1)
            k_cspmm<1><<<NBUCK, 1024, 0, stream>>>(starts, bulk, x, lie);
        else
            k_cspmm<0><<<NBUCK, 1024, 0, stream>>>(starts, bulk, x, lie);
        k_gemm<<<(NODES + 63) / 64, 256, 0, stream>>>(x, lie,
                                                      W1 + l * 4096, W2 + l * 4096,
                                                      b1 + l * 64,  b2 + l * 64);
        k_gather<<<(3 * BB * 64 + 255) / 256, 256, 0, stream>>>(x, su, oi, ui, out, l + 1);
    }
}

// Round 15
// 516.449 us; speedup vs baseline: 3.1303x; 1.0142x over previous
//
#include <hip/hip_runtime.h>

#define NN    60000
#define NODES 100000
#define DD    64
#define NNZ   3200000
#define BB    1024
#define NEG   0.2f
#define RPB   196                        // rows per bucket
#define NBUCK 511                        // ceil(NODES/RPB)
#define EPB   8192                       // edges per sort block
#define NPB   ((NNZ + EPB - 1) / EPB)    // 391
#define CAP   7000                       // bucket capacity (mean 6272, sd~79)
#define BCAP  7168                       // LDS edge capacity in k_csr
#define NSEG  13                         // column segments (col>>13), ~2 MB x-slice each
#define KEYN  (NSEG * RPB)               // 2548 sort keys per bucket
#define SPB   (KEYN + 1)                 // starts entries per bucket

// ---------------------------------------------------------------- init x = concat(eu, ei); also init gcur
__global__ __launch_bounds__(256) void k_init_x(const float* __restrict__ eu,
                                                const float* __restrict__ ei,
                                                float* __restrict__ x,
                                                int* __restrict__ gcur) {
    int i = blockIdx.x * 256 + threadIdx.x;          // float4 index
    if (i < NBUCK) gcur[i] = i * CAP;
    const int TOT = NODES * DD / 4;
    if (i >= TOT) return;
    const int UE = NN * DD / 4;
    float4 v = (i < UE) ? ((const float4*)eu)[i] : ((const float4*)ei)[i - UE];
    ((float4*)x)[i] = v;
}

// ---------------------------------------------------------------- bucket sort -> bulk
__global__ __launch_bounds__(512) void k_place(const int* __restrict__ row,
                                               const int* __restrict__ col,
                                               const float* __restrict__ val,
                                               int* __restrict__ gcur,
                                               int2* __restrict__ bulk) {
    __shared__ int rows_l[EPB];                // 32 KB
    __shared__ unsigned short perm[EPB];       // 16 KB
    __shared__ int h[NBUCK], bloc[NBUCK], bcur[NBUCK], gseg[NBUCK];
    __shared__ int sc[512];
    int t = threadIdx.x;
    if (t < NBUCK) h[t] = 0;
    __syncthreads();
    int base = blockIdx.x * EPB;
    int n = min(EPB, NNZ - base);
    for (int k = t; k < n; k += 512) {
        int r = row[base + k];
        rows_l[k] = r;
        atomicAdd(&h[r / RPB], 1);
    }
    __syncthreads();
    {
        int v = (t < NBUCK) ? h[t] : 0;
        sc[t] = v;
        __syncthreads();
        for (int off = 1; off < 512; off <<= 1) {
            int u = (t >= off) ? sc[t - off] : 0;
            __syncthreads();
            sc[t] += u;
            __syncthreads();
        }
        if (t < NBUCK) {
            int ex = sc[t] - v;
            bloc[t] = ex;
            bcur[t] = ex;
            gseg[t] = v ? atomicAdd(&gcur[t], v) : 0;
        }
    }
    __syncthreads();
    for (int k = t; k < n; k += 512) {
        int p = atomicAdd(&bcur[rows_l[k] / RPB], 1);
        perm[p] = (unsigned short)k;
    }
    __syncthreads();
    for (int j = t; j < n; j += 512) {
        int k = perm[j];
        int r = rows_l[k];
        int b = r / RPB;
        int addr = gseg[b] + (j - bloc[b]);
        bulk[addr] = make_int2(((r - b * RPB) << 17) | col[base + k],
                               __float_as_int(val[base + k]));
    }
}

// ---------------------------------------------------------------- per-bucket (colseg,row) sort
// in-place (keeps packed local-row bits); emit per-key span starts + sentinel
__global__ __launch_bounds__(512) void k_csr(const int* __restrict__ gcur,
                                             int2* __restrict__ bulk,
                                             int* __restrict__ starts) {
    __shared__ int2 eds[BCAP];                 // 56 KB
    __shared__ int cnt[KEYN], pos[KEYN];       // 20 KB
    __shared__ int part[512];
    int b = blockIdx.x, t = threadIdx.x;
    int lo = b * CAP;
    int n = gcur[b] - lo;
    for (int k = t; k < KEYN; k += 512) cnt[k] = 0;
    __syncthreads();
    for (int i = t; i < n; i += 512) {
        int2 ed = bulk[lo + i];
        eds[i] = ed;
        int lr = ed.x >> 17, c = ed.x & 0x1FFFF;
        atomicAdd(&cnt[(c >> 13) * RPB + lr], 1);
    }
    __syncthreads();
    // two-level exclusive scan over KEYN bins (5 bins/thread)
    int run = 0;
#pragma unroll
    for (int j = 0; j < 5; ++j) {
        int k = t * 5 + j;
        if (k < KEYN) { pos[k] = run; run += cnt[k]; }
    }
    part[t] = run;
    __syncthreads();
    for (int off = 1; off < 512; off <<= 1) {
        int u = (t >= off) ? part[t - off] : 0;
        __syncthreads();
        part[t] += u;
        __syncthreads();
    }
    int poff = part[t] - run;
#pragma unroll
    for (int j = 0; j < 5; ++j) {
        int k = t * 5 + j;
        if (k < KEYN) pos[k] += poff;
    }
    __syncthreads();
    for (int k = t; k < KEYN; k += 512) {
        starts[b * SPB + k] = lo + pos[k];
        cnt[k] = pos[k];                      // reuse as cursor
    }
    if (t == 0) starts[b * SPB + KEYN] = lo + n;
    __syncthreads();
    for (int i = t; i < n; i += 512) {
        int2 ed = eds[i];
        int lr = ed.x >> 17, c = ed.x & 0x1FFFF;
        int p = atomicAdd(&cnt[(c >> 13) * RPB + lr], 1);
        bulk[lo + p] = ed;                    // keep packed (lr<<17 | col)
    }
}

// ---------------------------------------------------------------- convoyed seg-major pull SpMM
// The session's verified best (83.9-84.2 us, R9 counters VGPR=12/SGPR=48):
// readfirstlane(wid) makes the whole address chain uniform -> the 8 cv loads
// compile to s_load (SMEM/lgkmcnt) and only gather results use VGPRs; 2-deep
// split-counter pipeline (meta on lgkmcnt, gathers on vmcnt) never drains
// both; run-length cur/f accumulate, LDS flush only on row change.
// Rejected by measurement: readlane broadcast 116, batch-64 109, LDS staging
// 157, vmcnt-shared pipeline 124, clamped BLK16 138, LDS f32 atomics 1053
// (gfx950 ds f32 atomics serialize per-lane), fused GEMM epilogue 149-490,
// clamped-tail A/B (co-compile perturbed codegen -> 92, rule #19).
__global__ __launch_bounds__(1024) void k_cspmm(const int* __restrict__ starts,
                                                const int2* __restrict__ cv,
                                                const float* __restrict__ x,
                                                float* __restrict__ lie) {
    __shared__ float acc[RPB * DD];            // 49 KB
    int t = threadIdx.x, b = blockIdx.x;
    float4* av = (float4*)acc;
    for (int i = t; i < RPB * 16; i += 1024) av[i] = make_float4(0.f, 0.f, 0.f, 0.f);
    __syncthreads();
    int lane = t & 63;
    int wid = __builtin_amdgcn_readfirstlane(t >> 6);   // provably wave-uniform
    int r0 = (wid * RPB) >> 4;
    int r1 = ((wid + 1) * RPB) >> 4;
    int sb = b * SPB;
    for (int seg = 0; seg < NSEG; ++seg) {
        int s = starts[sb + seg * RPB + r0];
        int e = starts[sb + seg * RPB + r1];   // r1==RPB -> next seg's r0 / sentinel
        int cur = -1;
        float f = 0.f;
        int2 emA[8], emB[8];
        float xwA[8], xwB[8];
#define LDM(S, gg) { _Pragma("unroll") \
    for (int j = 0; j < 8; ++j) em##S[j] = cv[(gg) + j]; }
#define GTH(S) { _Pragma("unroll") \
    for (int j = 0; j < 8; ++j) xw##S[j] = x[(em##S[j].x & 0x1FFFF) * DD + lane]; }
#define CNS(S) { _Pragma("unroll") \
    for (int j = 0; j < 8; ++j) { \
        int r = em##S[j].x >> 17; \
        if (r != cur) { if (cur >= 0) acc[cur * DD + lane] += f; cur = r; f = 0.f; } \
        f = fmaf(__int_as_float(em##S[j].y), xw##S[j], f); } }
        int nb = (e - s) >> 3;                 // full 8-blocks (uniform)
        if (nb > 0) {
            LDM(A, s) GTH(A)
            int ld = 1;
            for (;;) {
                if (ld < nb) { LDM(B, s + ld * 8) GTH(B) ++ld; CNS(A) }
                else         { CNS(A) break; }
                if (ld < nb) { LDM(A, s + ld * 8) GTH(A) ++ld; CNS(B) }
                else         { CNS(B) break; }
            }
        }
#undef LDM
#undef GTH
#undef CNS
        for (int g = s + nb * 8; g < e; ++g) {
            int2 ed = cv[g];
            float xg = x[(ed.x & 0x1FFFF) * DD + lane];
            int r = ed.x >> 17;
            if (r != cur) {
                if (cur >= 0) acc[cur * DD + lane] += f;
                cur = r; f = 0.f;
            }
            f = fmaf(__int_as_float(ed.y), xg, f);
        }
        if (cur >= 0) acc[cur * DD + lane] += f;
    }
    __syncthreads();
    int row0 = b * RPB;
    for (int i = t; i < RPB * 16; i += 1024) {
        int gr = row0 + (i >> 4);
        if (gr < NODES) ((float4*)lie)[gr * 16 + (i & 15)] = av[i];
    }
}

// ---------------------------------------------------------------- fused layer GEMM
__global__ __launch_bounds__(256) void k_gemm(float* __restrict__ x,
                                              const float* __restrict__ lie,
                                              const float* __restrict__ W1,
                                              const float* __restrict__ W2,
                                              const float* __restrict__ b1,
                                              const float* __restrict__ b2) {
    __shared__ float A1[64 * 64];
    __shared__ float A2[64 * 64];
    __shared__ float Ws1[64 * 64];
    __shared__ float Ws2[64 * 64];

    const int t = threadIdx.x;
    const int row0 = blockIdx.x * 64;

    {
        const float4* w1v = (const float4*)W1;
        const float4* w2v = (const float4*)W2;
        float4* s1v = (float4*)Ws1;
        float4* s2v = (float4*)Ws2;
#pragma unroll
        for (int q = 0; q < 4; ++q) {
            s1v[q * 256 + t] = w1v[q * 256 + t];
            s2v[q * 256 + t] = w2v[q * 256 + t];
        }
    }
#pragma unroll
    for (int q = 0; q < 4; ++q) {
        int f4 = q * 256 + t;
        int rl = f4 >> 4;
        int c4 = f4 & 15;
        int gr = row0 + rl;
        float4 lv = make_float4(0.f, 0.f, 0.f, 0.f);
        float4 xv = make_float4(0.f, 0.f, 0.f, 0.f);
        if (gr < NODES) {
            lv = *(const float4*)&lie[gr * DD + c4 * 4];
            xv = *(const float4*)&x[gr * DD + c4 * 4];
        }
        int sg = c4 ^ (rl & 15);
        ((float4*)A1)[rl * 16 + sg] = lv;
        ((float4*)A2)[rl * 16 + sg] = make_float4(lv.x * xv.x, lv.y * xv.y,
                                                  lv.z * xv.z, lv.w * xv.w);
    }
    __syncthreads();

    const int tx = t & 15;
    const int ty = t >> 4;
    float bs[4];
    {
        float4 bb1 = *(const float4*)&b1[tx * 4];
        float4 bb2 = *(const float4*)&b2[tx * 4];
        bs[0] = bb1.x + bb2.x; bs[1] = bb1.y + bb2.y;
        bs[2] = bb1.z + bb2.z; bs[3] = bb1.w + bb2.w;
    }
    float acc[4][4];
#pragma unroll
    for (int i = 0; i < 4; ++i)
#pragma unroll
        for (int j = 0; j < 4; ++j) acc[i][j] = bs[j];

    for (int k4 = 0; k4 < 16; ++k4) {
        float4 a1[4], a2[4];
#pragma unroll
        for (int i = 0; i < 4; ++i) {
            int r = ty * 4 + i;
            int sg = k4 ^ (r & 15);
            a1[i] = ((const float4*)A1)[r * 16 + sg];
            a2[i] = ((const float4*)A2)[r * 16 + sg];
        }
#pragma unroll
        for (int kk = 0; kk < 4; ++kk) {
            float4 w1 = ((const float4*)Ws1)[(k4 * 4 + kk) * 16 + tx];
            float4 w2 = ((const float4*)Ws2)[(k4 * 4 + kk) * 16 + tx];
#pragma unroll
            for (int i = 0; i < 4; ++i) {
                float av1 = (&a1[i].x)[kk];
                float av2 = (&a2[i].x)[kk];
                acc[i][0] = fmaf(av1, w1.x, fmaf(av2, w2.x, acc[i][0]));
                acc[i][1] = fmaf(av1, w1.y, fmaf(av2, w2.y, acc[i][1]));
                acc[i][2] = fmaf(av1, w1.z, fmaf(av2, w2.z, acc[i][2]));
                acc[i][3] = fmaf(av1, w1.w, fmaf(av2, w2.w, acc[i][3]));
            }
        }
    }
#pragma unroll
    for (int i = 0; i < 4; ++i) {
        int gr = row0 + ty * 4 + i;
        if (gr < NODES) {
            float4 o;
            o.x = acc[i][0] >= 0.f ? acc[i][0] : NEG * acc[i][0];
            o.y = acc[i][1] >= 0.f ? acc[i][1] : NEG * acc[i][1];
            o.z = acc[i][2] >= 0.f ? acc[i][2] : NEG * acc[i][2];
            o.w = acc[i][3] >= 0.f ? acc[i][3] : NEG * acc[i][3];
            *(float4*)&x[gr * DD + tx * 4] = o;
        }
    }
}

// ---------------------------------------------------------------- gather layer repr into output
__global__ __launch_bounds__(256) void k_gather(const float* __restrict__ x,
                                                const int* __restrict__ su,
                                                const int* __restrict__ oi,
                                                const int* __restrict__ ui,
                                                float* __restrict__ out, int layer) {
    int w    = (blockIdx.x * 256 + threadIdx.x) >> 6;
    int lane = threadIdx.x & 63;
    if (w >= 3 * BB) return;
    int g = w >> 10, b = w & 1023;
    int node = (g == 0) ? su[b] : (NN + ((g == 1) ? oi[b] : ui[b]));
    out[w * 256 + layer * 64 + lane] = x[node * DD + lane];
}

// ---------------------------------------------------------------- launch
extern "C" void kernel_launch(void* const* d_in, const int* in_sizes, int n_in,
                              void* d_out, int out_size, void* d_ws, size_t ws_size,
                              hipStream_t stream) {
    const int*   edge_row = (const int*)d_in[0];
    const int*   edge_col = (const int*)d_in[1];
    const float* edge_val = (const float*)d_in[2];
    const float* eu = (const float*)d_in[3];
    const float* ei = (const float*)d_in[4];
    const float* W1 = (const float*)d_in[5];
    const float* W2 = (const float*)d_in[6];
    const float* b1 = (const float*)d_in[7];
    const float* b2 = (const float*)d_in[8];
    const int*   su = (const int*)d_in[9];
    const int*   oi = (const int*)d_in[10];
    const int*   ui = (const int*)d_in[11];
    float* out = (float*)d_out;

    // workspace carve (~85 MB)
    float* x      = (float*)d_ws;                    // 25.6 MB
    float* lie    = x + NODES * DD;                  // 25.6 MB
    int2*  bulk   = (int2*)(lie + NODES * DD);       // NBUCK*CAP int2 (28.6 MB)
    int*   gcur   = (int*)(bulk + NBUCK * CAP);      // NBUCK
    int*   starts = gcur + NBUCK + 1;                // NBUCK*SPB (5.2 MB)

    k_init_x<<<(NODES * DD / 4 + 255) / 256, 256, 0, stream>>>(eu, ei, x, gcur);
    k_gather<<<(3 * BB * 64 + 255) / 256, 256, 0, stream>>>(x, su, oi, ui, out, 0);

    k_place<<<NPB, 512, 0, stream>>>(edge_row, edge_col, edge_val, gcur, bulk);
    k_csr<<<NBUCK, 512, 0, stream>>>(gcur, bulk, starts);

    for (int l = 0; l < 3; ++l) {
        k_cspmm<<<NBUCK, 1024, 0, stream>>>(starts, bulk, x, lie);
        k_gemm<<<(NODES + 63) / 64, 256, 0, stream>>>(x, lie,
                                                      W1 + l * 4096, W2 + l * 4096,
                                                      b1 + l * 64,  b2 + l * 64);
        k_gather<<<(3 * BB * 64 + 255) / 256, 256, 0, stream>>>(x, su, oi, ui, out, l + 1);
    }
}